// Round 21
// baseline (175.996 us; speedup 1.0000x reference)
//
#include <hip/hip_runtime.h>
#include <stdint.h>

// Problem constants
#define T_   2048
#define NH   16
#define HD   64
#define NBH  64     // B*H
#define CDIM 1024
#define MROWS 8192  // B*T

typedef __attribute__((ext_vector_type(8))) short short8;
typedef __attribute__((ext_vector_type(4))) float f32x4;
typedef __attribute__((ext_vector_type(16))) float f32x16;
typedef __attribute__((ext_vector_type(2))) unsigned int uint32x2;

#define LOG2E 1.44269504088896340736f

static __device__ __forceinline__ uint16_t f2bf(float f) {
  uint32_t u = __float_as_uint(f);
  return (uint16_t)((u + 0x7FFFu + ((u >> 16) & 1u)) >> 16);
}

static __device__ __forceinline__ void async16(const void* g, void* l) {
  __builtin_amdgcn_global_load_lds(
      (const __attribute__((address_space(1))) uint32_t*)g,
      (__attribute__((address_space(3))) uint32_t*)l, 16, 0, 0);
}

// permlane32_swap builtin: returns {vdst_new, vsrc_new}
static __device__ __forceinline__ uint32x2 plswap(uint32_t a, uint32_t b) {
  return __builtin_amdgcn_permlane32_swap(a, b, false, false);
}
static __device__ __forceinline__ float halves_max(float x) {
  uint32x2 r = plswap(__float_as_uint(x), __float_as_uint(x));
  return fmaxf(__uint_as_float(r[0]), __uint_as_float(r[1]));
}
static __device__ __forceinline__ float halves_sum(float x) {
  uint32x2 r = plswap(__float_as_uint(x), __float_as_uint(x));
  return __uint_as_float(r[0]) + __uint_as_float(r[1]);
}
static __device__ __forceinline__ uint32_t pkbf(float lo, float hi) {
  uint32_t r;
  asm("v_cvt_pk_bf16_f32 %0, %1, %2" : "=v"(r) : "v"(lo), "v"(hi));
  return r;
}
static __device__ __forceinline__ float tmax32(const f32x16& a, const f32x16& b) {
  float t[16];
#pragma unroll
  for (int r = 0; r < 16; ++r) t[r] = fmaxf(a[r], b[r]);
#pragma unroll
  for (int s = 8; s >= 1; s >>= 1)
#pragma unroll
    for (int r = 0; r < s; ++r) t[r] = fmaxf(t[r], t[r + s]);
  return t[0];
}
static __device__ __forceinline__ float tsum32(const f32x16& a, const f32x16& b) {
  float t[16];
#pragma unroll
  for (int r = 0; r < 16; ++r) t[r] = a[r] + b[r];
#pragma unroll
  for (int s = 8; s >= 1; s >>= 1)
#pragma unroll
    for (int r = 0; r < s; ++r) t[r] += t[r + s];
  return t[0];
}

// ---------------- fused fp32 -> bf16 convert (x, w_qkv, w_proj in one) ------
__global__ __launch_bounds__(256) void cvt3_f32_bf16(
    const float* __restrict__ a, uint16_t* __restrict__ oa, int na,
    const float* __restrict__ b, uint16_t* __restrict__ ob, int nb,
    const float* __restrict__ c, uint16_t* __restrict__ oc, int nc) {
  const int stride = gridDim.x * 256 * 4;
  for (int i = (blockIdx.x * 256 + threadIdx.x) * 4; i < na; i += stride) {
    float4 v = *(const float4*)(a + i);
    ushort4 o; o.x = f2bf(v.x); o.y = f2bf(v.y); o.z = f2bf(v.z); o.w = f2bf(v.w);
    *(ushort4*)(oa + i) = o;
  }
  for (int i = (blockIdx.x * 256 + threadIdx.x) * 4; i < nb; i += stride) {
    float4 v = *(const float4*)(b + i);
    ushort4 o; o.x = f2bf(v.x); o.y = f2bf(v.y); o.z = f2bf(v.z); o.w = f2bf(v.w);
    *(ushort4*)(ob + i) = o;
  }
  for (int i = (blockIdx.x * 256 + threadIdx.x) * 4; i < nc; i += stride) {
    float4 v = *(const float4*)(c + i);
    ushort4 o; o.x = f2bf(v.x); o.y = f2bf(v.y); o.z = f2bf(v.z); o.w = f2bf(v.w);
    *(ushort4*)(oc + i) = o;
  }
}

// ---------------- GEMM: C[M,N] = A[M,K] * Bt[N,K]^T (R17 known-best) --------
// 128x128 tile, BK=32, 4 waves (2x2 of 64x64), 16x16x32 bf16 MFMA.
// 16KB LDS -> 6 blocks/CU; inter-block overlap hides the per-tile vmcnt(0)
// drain. Default 2D dispatch order. 0-conflict both-sides XOR LDS swizzle.
// MODE 0: Cout fp32 = acc + bias[col] direct.
// MODE 1 (QKV): two-pass LDS-repack epilogue, 16B coalesced scatter stores.
template <int MODE>
__global__ __launch_bounds__(256) void gemm_bt(
    const uint16_t* __restrict__ A, const uint16_t* __restrict__ Bt,
    float* __restrict__ Cout, const float* __restrict__ bias,
    uint16_t* __restrict__ Qo, uint16_t* __restrict__ Ko, uint16_t* __restrict__ Vo,
    const int* __restrict__ perm, int N) {
  __shared__ __attribute__((aligned(16))) uint16_t lds[8192];  // 16KB
  uint16_t* lA = lds;           // [128*32]
  uint16_t* lB = lds + 4096;    // [128*32]

  const int t = threadIdx.x;
  const int lane = t & 63, wv = t >> 6;
  const int gq = lane >> 4, lc = lane & 15;
  const int mbase = blockIdx.x * 128;
  const int nbase = blockIdx.y * 128;
  const int wr = (wv >> 1) * 64, wc = (wv & 1) * 64;

  f32x4 acc[4][4];
#pragma unroll
  for (int i = 0; i < 4; ++i)
#pragma unroll
    for (int j = 0; j < 4; ++j) acc[i][j] = (f32x4){0.f, 0.f, 0.f, 0.f};

  const int srow = t >> 2;                              // 0..63 (per issue)
  const int scb  = (((t & 3) ^ ((t >> 3) & 3)) * 16);   // pre-swizzled source chunk (bytes)
  const int rxs  = (lc >> 1) & 3;                       // read-side slot XOR

  for (int kt = 0; kt < 32; ++kt) {
    const char* baseA = (const char*)A + ((size_t)mbase * CDIM + kt * 32) * 2;
    const char* baseB = (const char*)Bt + ((size_t)nbase * CDIM + kt * 32) * 2;
#pragma unroll
    for (int j = 0; j < 2; ++j) {
      int row = j * 64 + srow;
      async16(baseA + (size_t)row * (CDIM * 2) + scb, (char*)lA + j * 4096 + wv * 1024);
    }
#pragma unroll
    for (int j = 0; j < 2; ++j) {
      int row = j * 64 + srow;
      async16(baseB + (size_t)row * (CDIM * 2) + scb, (char*)lB + j * 4096 + wv * 1024);
    }
    asm volatile("s_waitcnt vmcnt(0)" ::: "memory");
    __syncthreads();

    short8 af[4], bfr[4];
#pragma unroll
    for (int mi = 0; mi < 4; ++mi)
      af[mi] = *(const short8*)&lA[(wr + mi * 16 + lc) * 32 + ((gq ^ rxs) * 8)];
#pragma unroll
    for (int ni = 0; ni < 4; ++ni)
      bfr[ni] = *(const short8*)&lB[(wc + ni * 16 + lc) * 32 + ((gq ^ rxs) * 8)];
#pragma unroll
    for (int mi = 0; mi < 4; ++mi)
#pragma unroll
      for (int ni = 0; ni < 4; ++ni)
        acc[mi][ni] = __builtin_amdgcn_mfma_f32_16x16x32_bf16(af[mi], bfr[ni], acc[mi][ni], 0, 0, 0);
    __syncthreads();
  }

  if (MODE == 0) {
#pragma unroll
    for (int mi = 0; mi < 4; ++mi) {
      int row = mbase + wr + mi * 16 + 4 * gq;
#pragma unroll
      for (int ni = 0; ni < 4; ++ni) {
        int col = nbase + wc + ni * 16 + lc;
        float bv = bias[col];
#pragma unroll
        for (int r = 0; r < 4; ++r)
          Cout[(size_t)(row + r) * N + col] = acc[mi][ni][r] + bv;
      }
    }
  } else {
    // ---- two-pass LDS-repack scatter epilogue ----
    const int wcw = wv & 1;  // which 64-col half this wave owns
    for (int pass = 0; pass < 2; ++pass) {
#pragma unroll
      for (int mi = 0; mi < 4; ++mi) {
#pragma unroll
        for (int nj = 0; nj < 2; ++nj) {
          int ni = 2 * pass + nj;
          int colg = nbase + wc + ni * 16 + lc;
          bool isQ = (colg < 1024);
          int c64 = wcw * 32 + nj * 16 + lc;
          int within = c64 & 7;
#pragma unroll
          for (int r = 0; r < 4; ++r) {
            int row = wr + mi * 16 + 4 * gq + r;         // 0..127
            int swz = ((row >> 2) & 3) << 1;
            int ch = (c64 >> 3) ^ swz;
            float v = acc[mi][ni][r];
            if (isQ) v *= (0.125f * LOG2E);
            lds[row * 64 + ch * 8 + within] = f2bf(v);
          }
        }
      }
      __syncthreads();
#pragma unroll
      for (int k = 0; k < 4; ++k) {
        int v = 256 * k + t;          // 0..1023
        int row = v >> 3;             // 0..127
        int ch = v & 7;
        int swz = ((row >> 2) & 3) << 1;
        short8 val = *(const short8*)&lds[row * 64 + ((ch ^ swz) * 8)];
        int m = mbase + row;
        int b = m >> 11, s = m & 2047;
        int p = perm[s];
        int colg = nbase + (ch >= 4 ? 64 : 0) + 32 * pass + (ch & 3) * 8;
        int typ = colg >> 10, cc = colg & 1023;
        int h = cc >> 6, d0 = cc & 63;
        int bh = b * 16 + h;
        if (typ == 0)
          *(short8*)(Qo + ((size_t)bh * T_ + s) * HD + d0) = val;
        else if (typ == 1)
          *(short8*)(Ko + ((size_t)bh * T_ + p) * HD + d0) = val;
        else
          *(short8*)(Vo + ((size_t)bh * T_ + p) * HD + d0) = val;
      }
      __syncthreads();
    }
  }
}

// ---------------- V transpose: [bh][p][d] -> [bh][d][p] ----------------
__global__ __launch_bounds__(256) void transpose_v(const uint16_t* __restrict__ Vp,
                                                   uint16_t* __restrict__ Vt) {
  __shared__ uint16_t tile[64][72];
  const int pb = blockIdx.x * 64;
  const int bh = blockIdx.y;
  const int t = threadIdx.x;
  const uint16_t* src = Vp + (size_t)bh * T_ * HD + (size_t)pb * HD;
#pragma unroll
  for (int it = 0; it < 2; ++it) {
    int lin = it * 256 + t;
    int row = lin >> 3, col = (lin & 7) * 8;
    short8 v = *(const short8*)(src + row * HD + col);
    *(short8*)&tile[row][col] = v;
  }
  __syncthreads();
  uint16_t* dst = Vt + (size_t)bh * HD * T_;
#pragma unroll
  for (int it = 0; it < 2; ++it) {
    int lin = it * 256 + t;
    int d = lin >> 3, ps = (lin & 7) * 8;
    short8 v;
#pragma unroll
    for (int j = 0; j < 8; ++j) v[j] = (short)tile[ps + j][d];
    *(short8*)(dst + (size_t)d * T_ + pb + ps) = v;
  }
}

// ---------------- causal flash attention, swapped-operand 32x32 ----------------
// R21: finer block granularity. 4 waves (256 thr); grid (64 bh, 16 y) with
// y -> (pair = y>>1, half = y&1). Waves 0-1 take heavy q-tile (15-pair),
// rows half*64+{0,32}; waves 2-3 the light tile pair. 1024 blocks = 4
// independent blocks/CU (vs R15's 2) — more latency-hiding contexts at the
// same 16 waves/CU; mirrors the gemm_bt high-block-count regime. Same math:
// swapped QK^T, tree reductions, defer-max (THR=8), cvt_pk+permlane P
// redistribution, O^T accumulation, dbuf raw-barrier loop, counted vmcnt(4).
__global__ __launch_bounds__(256, 4) void attn_kernel(
    const uint16_t* __restrict__ Q, const uint16_t* __restrict__ Kp,
    const uint16_t* __restrict__ Vt, uint16_t* __restrict__ Y) {
  __shared__ __attribute__((aligned(16))) uint16_t lK[2][64 * 64];
  __shared__ __attribute__((aligned(16))) uint16_t lV[2][64 * 64];

  const int bh = blockIdx.x;
  const int b = bh >> 4, h = bh & 15;
  const int y = blockIdx.y;                 // 0..15
  const int pair = y >> 1, half = y & 1;
  const int t = threadIdx.x;
  const int lane = t & 63, wv = t >> 6;     // 4 waves
  const int grp = wv >> 1;                  // 0 = heavy tile, 1 = light tile
  const int l31 = lane & 31, hi = lane >> 5;

  const int qtile = grp == 0 ? (15 - pair) : pair;
  const int qw = qtile * 128 + half * 64 + 32 * (wv & 1);
  const int qg = qw + l31;                  // this lane's q row (column of St)

  const uint16_t* Qb = Q + ((size_t)bh * T_ + qw) * HD;
  const uint16_t* Kb = Kp + (size_t)bh * T_ * HD;
  const uint16_t* Vb = Vt + (size_t)bh * HD * T_;

  const int srow8 = lane >> 3;               // 0..7
  const int schunk = (lane & 7) ^ srow8;     // swizzled source chunk (16B units)
  const int swz = (l31 & 7);                 // read-side XOR (row&7)

  short8 qf[4];
#pragma unroll
  for (int kc = 0; kc < 4; ++kc)
    qf[kc] = *(const short8*)(Qb + (size_t)l31 * HD + 16 * kc + 8 * hi);

  f32x16 ot[2];
#pragma unroll
  for (int dt = 0; dt < 2; ++dt)
#pragma unroll
    for (int r = 0; r < 16; ++r) ot[dt][r] = 0.f;
  float mrun = -__builtin_inff();
  float lrun = 0.f;

  // block kv-range covers its heavy waves: nkt = 2*(15-pair) + half + 1
  const int nkt_blk = 2 * (15 - pair) + half + 1;
  const int myKt = qw >> 6;                 // this wave's diagonal tile

  // staging: 16 x 1KB instrs per 64-key tile over 4 waves (4/wave);
  // i<8: K rows 8i.., i>=8: V rows 8(i-8)..
#define ASTAGE(pn, buf)                                                         \
  {                                                                             \
    _Pragma("unroll")                                                           \
    for (int j = 0; j < 4; ++j) {                                               \
      int i_ = 4 * wv + j;                                                      \
      if (i_ < 8)                                                               \
        async16(Kb + (size_t)((pn) + 8 * i_ + srow8) * HD + schunk * 8,         \
                (char*)&lK[buf][0] + i_ * 1024);                                \
      else                                                                      \
        async16(Vb + (size_t)(8 * (i_ - 8) + srow8) * T_ + (pn) + schunk * 8,   \
                (char*)&lV[buf][0] + (i_ - 8) * 1024);                          \
    }                                                                           \
  }

  ASTAGE(0, 0);

  for (int kt = 0; kt < nkt_blk; ++kt) {
    const int cur = kt & 1;
    const int p0 = kt * 64;
    if (kt + 1 < nkt_blk) {
      ASTAGE(p0 + 64, cur ^ 1);
      asm volatile("s_waitcnt vmcnt(4)" ::: "memory");  // kt landed; kt+1 in flight
    } else {
      asm volatile("s_waitcnt vmcnt(0)" ::: "memory");
    }
    __builtin_amdgcn_s_barrier();
    asm volatile("" ::: "memory");

    if (kt <= myKt) {
      const uint16_t* lk = &lK[cur][0];
      const uint16_t* lv = &lV[cur][0];

      f32x16 st[2];
#pragma unroll
      for (int a = 0; a < 2; ++a) {
        short8 kf[4];
#pragma unroll
        for (int kc = 0; kc < 4; ++kc)
          kf[kc] = *(const short8*)&lk[(32 * a + l31) * 64 + (((2 * kc + hi) ^ swz) * 8)];
#pragma unroll
        for (int r = 0; r < 16; ++r) st[a][r] = 0.f;
        __builtin_amdgcn_s_setprio(1);
#pragma unroll
        for (int kc = 0; kc < 4; ++kc)
          st[a] = __builtin_amdgcn_mfma_f32_32x32x16_bf16(kf[kc], qf[kc], st[a], 0, 0, 0);
        __builtin_amdgcn_s_setprio(0);
      }

      if (kt == myKt) {  // diagonal tile: mask key > q
#pragma unroll
        for (int a = 0; a < 2; ++a) {
          int kbase = p0 + 32 * a + 4 * hi;
#pragma unroll
          for (int r = 0; r < 16; ++r) {
            int key = kbase + (r & 3) + 8 * (r >> 2);
            if (key > qg) st[a][r] = -__builtin_inff();
          }
        }
      }

      float mall = halves_max(tmax32(st[0], st[1]));
      if (__any(mall > mrun + 8.0f)) {
        float mnew = fmaxf(mrun, mall);
        float alpha = __builtin_amdgcn_exp2f(mrun - mnew);
        mrun = mnew;
        lrun *= alpha;
#pragma unroll
        for (int dt = 0; dt < 2; ++dt)
#pragma unroll
          for (int r = 0; r < 16; ++r) ot[dt][r] *= alpha;
      }

#pragma unroll
      for (int a = 0; a < 2; ++a)
#pragma unroll
        for (int r = 0; r < 16; ++r)
          st[a][r] = __builtin_amdgcn_exp2f(st[a][r] - mrun);

      lrun += halves_sum(tsum32(st[0], st[1]));

      short8 pb[4];
#pragma unroll
      for (int kc = 0; kc < 4; ++kc) {
#define PV_(i) ((8 * kc + (i)) < 16 ? st[0][(8 * kc + (i)) & 15] : st[1][(8 * kc + (i)) & 15])
        uint32_t u0 = pkbf(PV_(0), PV_(1));
        uint32_t u1 = pkbf(PV_(2), PV_(3));
        uint32_t u2 = pkbf(PV_(4), PV_(5));
        uint32_t u3 = pkbf(PV_(6), PV_(7));
#undef PV_
        uint32x2 s02 = plswap(u0, u2);
        uint32x2 s13 = plswap(u1, u3);
        union { uint32_t w[4]; short8 s; } pbu;
        pbu.w[0] = s02[0]; pbu.w[1] = s13[0]; pbu.w[2] = s02[1]; pbu.w[3] = s13[1];
        pb[kc] = pbu.s;
      }

#pragma unroll
      for (int dt = 0; dt < 2; ++dt) {
        short8 vf[4];
#pragma unroll
        for (int kc = 0; kc < 4; ++kc)
          vf[kc] = *(const short8*)&lv[(32 * dt + l31) * 64 + (((2 * kc + hi) ^ swz) * 8)];
        __builtin_amdgcn_s_setprio(1);
#pragma unroll
        for (int kc = 0; kc < 4; ++kc)
          ot[dt] = __builtin_amdgcn_mfma_f32_32x32x16_bf16(vf[kc], pb[kc], ot[dt], 0, 0, 0);
        __builtin_amdgcn_s_setprio(0);
      }
    }
    asm volatile("" ::: "memory");
    __builtin_amdgcn_s_barrier();
  }
#undef ASTAGE

  // epilogue: O^T[d][q]/l -> Y[b*T+q][h*64+d], 8B packed stores
  float inv = 1.0f / lrun;
  uint16_t* Yrow = Y + ((size_t)b * T_ + qg) * CDIM + h * HD;
#pragma unroll
  for (int dt = 0; dt < 2; ++dt)
#pragma unroll
    for (int g = 0; g < 4; ++g) {
      int d0 = 32 * dt + 8 * g + 4 * hi;
      ushort4 o4;
      o4.x = f2bf(ot[dt][4 * g + 0] * inv);
      o4.y = f2bf(ot[dt][4 * g + 1] * inv);
      o4.z = f2bf(ot[dt][4 * g + 2] * inv);
      o4.w = f2bf(ot[dt][4 * g + 3] * inv);
      *(ushort4*)(Yrow + d0) = o4;
    }
}

// ---------------- launch ----------------
extern "C" void kernel_launch(void* const* d_in, const int* in_sizes, int n_in,
                              void* d_out, int out_size, void* d_ws, size_t ws_size,
                              hipStream_t stream) {
  const float* x = (const float*)d_in[0];
  const float* wqkv = (const float*)d_in[1];
  const float* wproj = (const float*)d_in[2];
  const float* bproj = (const float*)d_in[3];
  const int* perm = (const int*)d_in[4];
  float* out = (float*)d_out;

  char* ws = (char*)d_ws;
  uint16_t* xb     = (uint16_t*)(ws + 0);          // 16 MB (reused as Y later)
  uint16_t* wqkvb  = (uint16_t*)(ws + 16777216);   // 6 MB
  uint16_t* wprojb = (uint16_t*)(ws + 23068672);   // 2 MB
  uint16_t* Qb     = (uint16_t*)(ws + 25165824);   // 16 MB
  uint16_t* Kb     = (uint16_t*)(ws + 41943040);   // 16 MB
  uint16_t* Vpb    = (uint16_t*)(ws + 58720256);   // 16 MB
  uint16_t* Vtb    = (uint16_t*)(ws + 75497472);   // 16 MB
  uint16_t* Yb     = xb;                           // reuse (x no longer needed)

  cvt3_f32_bf16<<<2048, 256, 0, stream>>>(x, xb, MROWS * CDIM,
                                          wqkv, wqkvb, 3 * CDIM * CDIM,
                                          wproj, wprojb, CDIM * CDIM);

  gemm_bt<1><<<dim3(64, 24), 256, 0, stream>>>(xb, wqkvb, nullptr, nullptr,
                                               Qb, Kb, Vpb, perm, 3072);
  transpose_v<<<dim3(32, 64), 256, 0, stream>>>(Vpb, Vtb);
  attn_kernel<<<dim3(64, 16), 256, 0, stream>>>(Qb, Kb, Vtb, Yb);
  gemm_bt<0><<<dim3(64, 8), 256, 0, stream>>>(Yb, wprojb, out, bproj,
                                              nullptr, nullptr, nullptr, nullptr, CDIM);
}

// Round 22
// 164.126 us; speedup vs baseline: 1.0723x; 1.0723x over previous
//
#include <hip/hip_runtime.h>
#include <stdint.h>

// Problem constants
#define T_   2048
#define NH   16
#define HD   64
#define NBH  64     // B*H
#define CDIM 1024
#define MROWS 8192  // B*T

typedef __attribute__((ext_vector_type(8))) short short8;
typedef __attribute__((ext_vector_type(4))) float f32x4;
typedef __attribute__((ext_vector_type(16))) float f32x16;
typedef __attribute__((ext_vector_type(2))) unsigned int uint32x2;

#define LOG2E 1.44269504088896340736f

static __device__ __forceinline__ uint16_t f2bf(float f) {
  uint32_t u = __float_as_uint(f);
  return (uint16_t)((u + 0x7FFFu + ((u >> 16) & 1u)) >> 16);
}

static __device__ __forceinline__ void async16(const void* g, void* l) {
  __builtin_amdgcn_global_load_lds(
      (const __attribute__((address_space(1))) uint32_t*)g,
      (__attribute__((address_space(3))) uint32_t*)l, 16, 0, 0);
}

// permlane32_swap builtin: returns {vdst_new, vsrc_new}
static __device__ __forceinline__ uint32x2 plswap(uint32_t a, uint32_t b) {
  return __builtin_amdgcn_permlane32_swap(a, b, false, false);
}
static __device__ __forceinline__ float halves_max(float x) {
  uint32x2 r = plswap(__float_as_uint(x), __float_as_uint(x));
  return fmaxf(__uint_as_float(r[0]), __uint_as_float(r[1]));
}
static __device__ __forceinline__ float halves_sum(float x) {
  uint32x2 r = plswap(__float_as_uint(x), __float_as_uint(x));
  return __uint_as_float(r[0]) + __uint_as_float(r[1]);
}
static __device__ __forceinline__ uint32_t pkbf(float lo, float hi) {
  uint32_t r;
  asm("v_cvt_pk_bf16_f32 %0, %1, %2" : "=v"(r) : "v"(lo), "v"(hi));
  return r;
}
static __device__ __forceinline__ float tmax32(const f32x16& a, const f32x16& b) {
  float t[16];
#pragma unroll
  for (int r = 0; r < 16; ++r) t[r] = fmaxf(a[r], b[r]);
#pragma unroll
  for (int s = 8; s >= 1; s >>= 1)
#pragma unroll
    for (int r = 0; r < s; ++r) t[r] = fmaxf(t[r], t[r + s]);
  return t[0];
}
static __device__ __forceinline__ float tsum32(const f32x16& a, const f32x16& b) {
  float t[16];
#pragma unroll
  for (int r = 0; r < 16; ++r) t[r] = a[r] + b[r];
#pragma unroll
  for (int s = 8; s >= 1; s >>= 1)
#pragma unroll
    for (int r = 0; r < s; ++r) t[r] += t[r + s];
  return t[0];
}

// ---------------- fused fp32 -> bf16 convert (x, w_qkv, w_proj in one) ------
__global__ __launch_bounds__(256) void cvt3_f32_bf16(
    const float* __restrict__ a, uint16_t* __restrict__ oa, int na,
    const float* __restrict__ b, uint16_t* __restrict__ ob, int nb,
    const float* __restrict__ c, uint16_t* __restrict__ oc, int nc) {
  const int stride = gridDim.x * 256 * 4;
  for (int i = (blockIdx.x * 256 + threadIdx.x) * 4; i < na; i += stride) {
    float4 v = *(const float4*)(a + i);
    ushort4 o; o.x = f2bf(v.x); o.y = f2bf(v.y); o.z = f2bf(v.z); o.w = f2bf(v.w);
    *(ushort4*)(oa + i) = o;
  }
  for (int i = (blockIdx.x * 256 + threadIdx.x) * 4; i < nb; i += stride) {
    float4 v = *(const float4*)(b + i);
    ushort4 o; o.x = f2bf(v.x); o.y = f2bf(v.y); o.z = f2bf(v.z); o.w = f2bf(v.w);
    *(ushort4*)(ob + i) = o;
  }
  for (int i = (blockIdx.x * 256 + threadIdx.x) * 4; i < nc; i += stride) {
    float4 v = *(const float4*)(c + i);
    ushort4 o; o.x = f2bf(v.x); o.y = f2bf(v.y); o.z = f2bf(v.z); o.w = f2bf(v.w);
    *(ushort4*)(oc + i) = o;
  }
}

// ---------------- GEMM: C[M,N] = A[M,K] * Bt[N,K]^T (known-best) --------
// 128x128 tile, BK=32, 4 waves (2x2 of 64x64), 16x16x32 bf16 MFMA.
// 16KB LDS -> 6 blocks/CU; inter-block overlap hides the per-tile vmcnt(0)
// drain. Default 2D dispatch order. 0-conflict both-sides XOR LDS swizzle.
// MODE 0: Cout fp32 = acc + bias[col] direct.
// MODE 1 (QKV): two-pass LDS-repack epilogue, 16B coalesced scatter stores.
template <int MODE>
__global__ __launch_bounds__(256) void gemm_bt(
    const uint16_t* __restrict__ A, const uint16_t* __restrict__ Bt,
    float* __restrict__ Cout, const float* __restrict__ bias,
    uint16_t* __restrict__ Qo, uint16_t* __restrict__ Ko, uint16_t* __restrict__ Vo,
    const int* __restrict__ perm, int N) {
  __shared__ __attribute__((aligned(16))) uint16_t lds[8192];  // 16KB
  uint16_t* lA = lds;           // [128*32]
  uint16_t* lB = lds + 4096;    // [128*32]

  const int t = threadIdx.x;
  const int lane = t & 63, wv = t >> 6;
  const int gq = lane >> 4, lc = lane & 15;
  const int mbase = blockIdx.x * 128;
  const int nbase = blockIdx.y * 128;
  const int wr = (wv >> 1) * 64, wc = (wv & 1) * 64;

  f32x4 acc[4][4];
#pragma unroll
  for (int i = 0; i < 4; ++i)
#pragma unroll
    for (int j = 0; j < 4; ++j) acc[i][j] = (f32x4){0.f, 0.f, 0.f, 0.f};

  const int srow = t >> 2;                              // 0..63 (per issue)
  const int scb  = (((t & 3) ^ ((t >> 3) & 3)) * 16);   // pre-swizzled source chunk (bytes)
  const int rxs  = (lc >> 1) & 3;                       // read-side slot XOR

  for (int kt = 0; kt < 32; ++kt) {
    const char* baseA = (const char*)A + ((size_t)mbase * CDIM + kt * 32) * 2;
    const char* baseB = (const char*)Bt + ((size_t)nbase * CDIM + kt * 32) * 2;
#pragma unroll
    for (int j = 0; j < 2; ++j) {
      int row = j * 64 + srow;
      async16(baseA + (size_t)row * (CDIM * 2) + scb, (char*)lA + j * 4096 + wv * 1024);
    }
#pragma unroll
    for (int j = 0; j < 2; ++j) {
      int row = j * 64 + srow;
      async16(baseB + (size_t)row * (CDIM * 2) + scb, (char*)lB + j * 4096 + wv * 1024);
    }
    asm volatile("s_waitcnt vmcnt(0)" ::: "memory");
    __syncthreads();

    short8 af[4], bfr[4];
#pragma unroll
    for (int mi = 0; mi < 4; ++mi)
      af[mi] = *(const short8*)&lA[(wr + mi * 16 + lc) * 32 + ((gq ^ rxs) * 8)];
#pragma unroll
    for (int ni = 0; ni < 4; ++ni)
      bfr[ni] = *(const short8*)&lB[(wc + ni * 16 + lc) * 32 + ((gq ^ rxs) * 8)];
#pragma unroll
    for (int mi = 0; mi < 4; ++mi)
#pragma unroll
      for (int ni = 0; ni < 4; ++ni)
        acc[mi][ni] = __builtin_amdgcn_mfma_f32_16x16x32_bf16(af[mi], bfr[ni], acc[mi][ni], 0, 0, 0);
    __syncthreads();
  }

  if (MODE == 0) {
#pragma unroll
    for (int mi = 0; mi < 4; ++mi) {
      int row = mbase + wr + mi * 16 + 4 * gq;
#pragma unroll
      for (int ni = 0; ni < 4; ++ni) {
        int col = nbase + wc + ni * 16 + lc;
        float bv = bias[col];
#pragma unroll
        for (int r = 0; r < 4; ++r)
          Cout[(size_t)(row + r) * N + col] = acc[mi][ni][r] + bv;
      }
    }
  } else {
    // ---- two-pass LDS-repack scatter epilogue ----
    const int wcw = wv & 1;  // which 64-col half this wave owns
    for (int pass = 0; pass < 2; ++pass) {
#pragma unroll
      for (int mi = 0; mi < 4; ++mi) {
#pragma unroll
        for (int nj = 0; nj < 2; ++nj) {
          int ni = 2 * pass + nj;
          int colg = nbase + wc + ni * 16 + lc;
          bool isQ = (colg < 1024);
          int c64 = wcw * 32 + nj * 16 + lc;
          int within = c64 & 7;
#pragma unroll
          for (int r = 0; r < 4; ++r) {
            int row = wr + mi * 16 + 4 * gq + r;         // 0..127
            int swz = ((row >> 2) & 3) << 1;
            int ch = (c64 >> 3) ^ swz;
            float v = acc[mi][ni][r];
            if (isQ) v *= (0.125f * LOG2E);
            lds[row * 64 + ch * 8 + within] = f2bf(v);
          }
        }
      }
      __syncthreads();
#pragma unroll
      for (int k = 0; k < 4; ++k) {
        int v = 256 * k + t;          // 0..1023
        int row = v >> 3;             // 0..127
        int ch = v & 7;
        int swz = ((row >> 2) & 3) << 1;
        short8 val = *(const short8*)&lds[row * 64 + ((ch ^ swz) * 8)];
        int m = mbase + row;
        int b = m >> 11, s = m & 2047;
        int p = perm[s];
        int colg = nbase + (ch >= 4 ? 64 : 0) + 32 * pass + (ch & 3) * 8;
        int typ = colg >> 10, cc = colg & 1023;
        int h = cc >> 6, d0 = cc & 63;
        int bh = b * 16 + h;
        if (typ == 0)
          *(short8*)(Qo + ((size_t)bh * T_ + s) * HD + d0) = val;
        else if (typ == 1)
          *(short8*)(Ko + ((size_t)bh * T_ + p) * HD + d0) = val;
        else
          *(short8*)(Vo + ((size_t)bh * T_ + p) * HD + d0) = val;
      }
      __syncthreads();
    }
  }
}

// ---------------- V transpose: [bh][p][d] -> [bh][d][p] ----------------
__global__ __launch_bounds__(256) void transpose_v(const uint16_t* __restrict__ Vp,
                                                   uint16_t* __restrict__ Vt) {
  __shared__ uint16_t tile[64][72];
  const int pb = blockIdx.x * 64;
  const int bh = blockIdx.y;
  const int t = threadIdx.x;
  const uint16_t* src = Vp + (size_t)bh * T_ * HD + (size_t)pb * HD;
#pragma unroll
  for (int it = 0; it < 2; ++it) {
    int lin = it * 256 + t;
    int row = lin >> 3, col = (lin & 7) * 8;
    short8 v = *(const short8*)(src + row * HD + col);
    *(short8*)&tile[row][col] = v;
  }
  __syncthreads();
  uint16_t* dst = Vt + (size_t)bh * HD * T_;
#pragma unroll
  for (int it = 0; it < 2; ++it) {
    int lin = it * 256 + t;
    int d = lin >> 3, ps = (lin & 7) * 8;
    short8 v;
#pragma unroll
    for (int j = 0; j < 8; ++j) v[j] = (short)tile[ps + j][d];
    *(short8*)(dst + (size_t)d * T_ + pb + ps) = v;
  }
}

// ---------------- causal flash attention, swapped-operand 32x32 ----------------
// Known-best (R15): concurrent pairing with shared staging. 8 waves (512
// thr): waves 0-3 process heavy q-tile (15-p)*128, waves 4-7 the
// complementary light tile p*128, SHARING one K/V LDS staging stream (16
// gload_lds per tile over 8 waves = 2/wave). 32KB LDS -> 2 blocks/CU = 16
// waves/CU. 512 blocks resident from t=0; blockIdx.y remap pairs (p, 7-p)
// per CU -> uniform work. Swapped QK^T (St = mfma(K,Q)), tree reductions,
// defer-max (THR=8), cvt_pk+permlane P redistribution, O^T accumulation,
// raw-barrier dbuf loop with counted vmcnt(2). Both coarser (R13 serial
// pairing) and finer (R21 4-wave) granularity regressed.
__global__ __launch_bounds__(512, 4) void attn_kernel(
    const uint16_t* __restrict__ Q, const uint16_t* __restrict__ Kp,
    const uint16_t* __restrict__ Vt, uint16_t* __restrict__ Y) {
  __shared__ __attribute__((aligned(16))) uint16_t lK[2][64 * 64];
  __shared__ __attribute__((aligned(16))) uint16_t lV[2][64 * 64];

  const int bh = blockIdx.x;
  const int b = bh >> 4, h = bh & 15;
  const int y = blockIdx.y;                 // 0..7
  const int pp = (y < 4) ? y : 11 - y;      // CU-pairing remap {0..3,7..4}
  const int t = threadIdx.x;
  const int lane = t & 63, wv = t >> 6;     // 8 waves
  const int grp = wv >> 2;                  // 0 = heavy tile, 1 = light tile
  const int wq = wv & 3;
  const int l31 = lane & 31, hi = lane >> 5;

  const int qtile = grp == 0 ? (15 - pp) : pp;
  const int qb = qtile * 128;
  const int qw = qb + 32 * wq;
  const int qg = qw + l31;                  // this lane's q row (column of St)

  const uint16_t* Qb = Q + ((size_t)bh * T_ + qw) * HD;
  const uint16_t* Kb = Kp + (size_t)bh * T_ * HD;
  const uint16_t* Vb = Vt + (size_t)bh * HD * T_;

  const int srow8 = lane >> 3;               // 0..7
  const int schunk = (lane & 7) ^ srow8;     // swizzled source chunk (16B units)
  const int swz = (l31 & 7);                 // read-side XOR (row&7)

  short8 qf[4];
#pragma unroll
  for (int kc = 0; kc < 4; ++kc)
    qf[kc] = *(const short8*)(Qb + (size_t)l31 * HD + 16 * kc + 8 * hi);

  f32x16 ot[2];
#pragma unroll
  for (int dt = 0; dt < 2; ++dt)
#pragma unroll
    for (int r = 0; r < 16; ++r) ot[dt][r] = 0.f;
  float mrun = -__builtin_inff();
  float lrun = 0.f;

  const int nkt_blk = 2 * (15 - pp) + 2;    // heavy tile's kv range (block-uniform)
  const int myKt = qw >> 6;                 // this wave's diagonal tile

  // staging: 16 x 1KB instrs per 64-key tile (i<8: K rows 8i.., i>=8: V rows)
#define ASTAGE(pn, buf)                                                         \
  {                                                                             \
    _Pragma("unroll")                                                           \
    for (int j = 0; j < 2; ++j) {                                               \
      int i_ = 2 * wv + j;                                                      \
      if (i_ < 8)                                                               \
        async16(Kb + (size_t)((pn) + 8 * i_ + srow8) * HD + schunk * 8,         \
                (char*)&lK[buf][0] + i_ * 1024);                                \
      else                                                                      \
        async16(Vb + (size_t)(8 * (i_ - 8) + srow8) * T_ + (pn) + schunk * 8,   \
                (char*)&lV[buf][0] + (i_ - 8) * 1024);                          \
    }                                                                           \
  }

  ASTAGE(0, 0);

  for (int kt = 0; kt < nkt_blk; ++kt) {
    const int cur = kt & 1;
    const int p0 = kt * 64;
    if (kt + 1 < nkt_blk) {
      ASTAGE(p0 + 64, cur ^ 1);
      asm volatile("s_waitcnt vmcnt(2)" ::: "memory");  // kt landed; kt+1 in flight
    } else {
      asm volatile("s_waitcnt vmcnt(0)" ::: "memory");
    }
    __builtin_amdgcn_s_barrier();
    asm volatile("" ::: "memory");

    if (kt <= myKt) {
      const uint16_t* lk = &lK[cur][0];
      const uint16_t* lv = &lV[cur][0];

      f32x16 st[2];
#pragma unroll
      for (int a = 0; a < 2; ++a) {
        short8 kf[4];
#pragma unroll
        for (int kc = 0; kc < 4; ++kc)
          kf[kc] = *(const short8*)&lk[(32 * a + l31) * 64 + (((2 * kc + hi) ^ swz) * 8)];
#pragma unroll
        for (int r = 0; r < 16; ++r) st[a][r] = 0.f;
        __builtin_amdgcn_s_setprio(1);
#pragma unroll
        for (int kc = 0; kc < 4; ++kc)
          st[a] = __builtin_amdgcn_mfma_f32_32x32x16_bf16(kf[kc], qf[kc], st[a], 0, 0, 0);
        __builtin_amdgcn_s_setprio(0);
      }

      if (kt == myKt) {  // diagonal tile: mask key > q
#pragma unroll
        for (int a = 0; a < 2; ++a) {
          int kbase = p0 + 32 * a + 4 * hi;
#pragma unroll
          for (int r = 0; r < 16; ++r) {
            int key = kbase + (r & 3) + 8 * (r >> 2);
            if (key > qg) st[a][r] = -__builtin_inff();
          }
        }
      }

      float mall = halves_max(tmax32(st[0], st[1]));
      if (__any(mall > mrun + 8.0f)) {
        float mnew = fmaxf(mrun, mall);
        float alpha = __builtin_amdgcn_exp2f(mrun - mnew);
        mrun = mnew;
        lrun *= alpha;
#pragma unroll
        for (int dt = 0; dt < 2; ++dt)
#pragma unroll
          for (int r = 0; r < 16; ++r) ot[dt][r] *= alpha;
      }

#pragma unroll
      for (int a = 0; a < 2; ++a)
#pragma unroll
        for (int r = 0; r < 16; ++r)
          st[a][r] = __builtin_amdgcn_exp2f(st[a][r] - mrun);

      lrun += halves_sum(tsum32(st[0], st[1]));

      short8 pb[4];
#pragma unroll
      for (int kc = 0; kc < 4; ++kc) {
#define PV_(i) ((8 * kc + (i)) < 16 ? st[0][(8 * kc + (i)) & 15] : st[1][(8 * kc + (i)) & 15])
        uint32_t u0 = pkbf(PV_(0), PV_(1));
        uint32_t u1 = pkbf(PV_(2), PV_(3));
        uint32_t u2 = pkbf(PV_(4), PV_(5));
        uint32_t u3 = pkbf(PV_(6), PV_(7));
#undef PV_
        uint32x2 s02 = plswap(u0, u2);
        uint32x2 s13 = plswap(u1, u3);
        union { uint32_t w[4]; short8 s; } pbu;
        pbu.w[0] = s02[0]; pbu.w[1] = s13[0]; pbu.w[2] = s02[1]; pbu.w[3] = s13[1];
        pb[kc] = pbu.s;
      }

#pragma unroll
      for (int dt = 0; dt < 2; ++dt) {
        short8 vf[4];
#pragma unroll
        for (int kc = 0; kc < 4; ++kc)
          vf[kc] = *(const short8*)&lv[(32 * dt + l31) * 64 + (((2 * kc + hi) ^ swz) * 8)];
        __builtin_amdgcn_s_setprio(1);
#pragma unroll
        for (int kc = 0; kc < 4; ++kc)
          ot[dt] = __builtin_amdgcn_mfma_f32_32x32x16_bf16(vf[kc], pb[kc], ot[dt], 0, 0, 0);
        __builtin_amdgcn_s_setprio(0);
      }
    }
    asm volatile("" ::: "memory");
    __builtin_amdgcn_s_barrier();
  }
#undef ASTAGE

  // epilogue: O^T[d][q]/l -> Y[b*T+q][h*64+d], 8B packed stores
  float inv = 1.0f / lrun;
  uint16_t* Yrow = Y + ((size_t)b * T_ + qg) * CDIM + h * HD;
#pragma unroll
  for (int dt = 0; dt < 2; ++dt)
#pragma unroll
    for (int g = 0; g < 4; ++g) {
      int d0 = 32 * dt + 8 * g + 4 * hi;
      ushort4 o4;
      o4.x = f2bf(ot[dt][4 * g + 0] * inv);
      o4.y = f2bf(ot[dt][4 * g + 1] * inv);
      o4.z = f2bf(ot[dt][4 * g + 2] * inv);
      o4.w = f2bf(ot[dt][4 * g + 3] * inv);
      *(ushort4*)(Yrow + d0) = o4;
    }
}

// ---------------- launch ----------------
extern "C" void kernel_launch(void* const* d_in, const int* in_sizes, int n_in,
                              void* d_out, int out_size, void* d_ws, size_t ws_size,
                              hipStream_t stream) {
  const float* x = (const float*)d_in[0];
  const float* wqkv = (const float*)d_in[1];
  const float* wproj = (const float*)d_in[2];
  const float* bproj = (const float*)d_in[3];
  const int* perm = (const int*)d_in[4];
  float* out = (float*)d_out;

  char* ws = (char*)d_ws;
  uint16_t* xb     = (uint16_t*)(ws + 0);          // 16 MB (reused as Y later)
  uint16_t* wqkvb  = (uint16_t*)(ws + 16777216);   // 6 MB
  uint16_t* wprojb = (uint16_t*)(ws + 23068672);   // 2 MB
  uint16_t* Qb     = (uint16_t*)(ws + 25165824);   // 16 MB
  uint16_t* Kb     = (uint16_t*)(ws + 41943040);   // 16 MB
  uint16_t* Vpb    = (uint16_t*)(ws + 58720256);   // 16 MB
  uint16_t* Vtb    = (uint16_t*)(ws + 75497472);   // 16 MB
  uint16_t* Yb     = xb;                           // reuse (x no longer needed)

  cvt3_f32_bf16<<<2048, 256, 0, stream>>>(x, xb, MROWS * CDIM,
                                          wqkv, wqkvb, 3 * CDIM * CDIM,
                                          wproj, wprojb, CDIM * CDIM);

  gemm_bt<1><<<dim3(64, 24), 256, 0, stream>>>(xb, wqkvb, nullptr, nullptr,
                                               Qb, Kb, Vpb, perm, 3072);
  transpose_v<<<dim3(32, 64), 256, 0, stream>>>(Vpb, Vtb);
  attn_kernel<<<dim3(64, 8), 512, 0, stream>>>(Qb, Kb, Vtb, Yb);
  gemm_bt<0><<<dim3(64, 8), 256, 0, stream>>>(Yb, wprojb, out, bproj,
                                              nullptr, nullptr, nullptr, nullptr, CDIM);
}